// Round 9
// baseline (326.713 us; speedup 1.0000x reference)
//
#include <hip/hip_runtime.h>
#include <cstdint>
#include <cstddef>

#define Tt 2048
#define Bb 2
#define Ee 1024
#define Hh 16
#define HD 64
#define BHh (Bb*Hh)
#define Mm (Tt*Bb)

typedef short bf16x8 __attribute__((ext_vector_type(8)));
typedef float f32x4  __attribute__((ext_vector_type(4)));

#define MFMA16(a,b,c) __builtin_amdgcn_mfma_f32_16x16x32_bf16(a, b, c, 0, 0, 0)

// Software RNE f32->bf16 (R7-validated; do NOT use v_cvt_pk_bf16_f32 —
// R8 failed with error magnitude matching a truncation-bias, absmax 1e-2).
__device__ __forceinline__ unsigned short f2bf(float f) {
    unsigned int u = __builtin_bit_cast(unsigned int, f);
    u += 0x7FFFu + ((u >> 16) & 1u);        // RNE
    return (unsigned short)(u >> 16);
}
__device__ __forceinline__ unsigned int pack2bf(float lo, float hi) {
    return (unsigned int)f2bf(lo) | ((unsigned int)f2bf(hi) << 16);
}

// --- LDS fragment loads, pitch 72 ushorts (144B rows, 16B-aligned) ---------
// Contiguous-8 k-slot convention (slot j -> col+j): ONE ds_read_b128.
// Valid for any LDS<->LDS operand pair sharing the same k-map (MFMA pairs
// A/B slots positionally; permutation-invariant).
__device__ __forceinline__ bf16x8 ldfrag8(const unsigned short* base, int row, int col) {
    return __builtin_bit_cast(bf16x8, *(const uint4*)(base + row*72 + col));
}
// Split convention (slot j<4 -> col+j, j>=4 -> col+16+(j-4)): 2x ds_read_b64.
// REQUIRED for PV's V operand: P's k-slot map is forced by QK's D-layout.
__device__ __forceinline__ bf16x8 ldfragV(const unsigned short* base, int row, int col) {
    const uint2 a = *(const uint2*)(base + row*72 + col);
    const uint2 b = *(const uint2*)(base + row*72 + col + 16);
    const uint4 u = {a.x, a.y, b.x, b.y};
    return __builtin_bit_cast(bf16x8, u);
}

// ---------------------------------------------------------------------------
// MFMA GEMM: C[M,N] = A[M,K] * W[N,K]^T + bias[N], f32 inputs cast to bf16.
// 128x128 tile, BK=32, 4 waves (2x2), wave = 64x64 out.
// MODE 0: scatter into head-major Q/K/V (scale Q by 0.125). MODE 1: plain.
// ---------------------------------------------------------------------------
template<int MODE>
__global__ __launch_bounds__(256)
void gemm_mfma(const float* __restrict__ A, const float* __restrict__ W,
               const float* __restrict__ bias, float* __restrict__ Cout,
               float* __restrict__ qbuf, float* __restrict__ kbuf,
               float* __restrict__ vbuf, int N, int K)
{
    __shared__ __align__(16) unsigned short As[128][72];
    __shared__ __align__(16) unsigned short Ws[128][72];
    const int tid  = threadIdx.x;
    const int bm   = blockIdx.y * 128;
    const int bn   = blockIdx.x * 128;
    const int w    = tid >> 6;
    const int lane = tid & 63;
    const int lr   = lane & 15;
    const int lg   = lane >> 4;
    const int wm   = (w >> 1) * 64;
    const int wn   = (w & 1) * 64;

    f32x4 acc[4][4];
#pragma unroll
    for (int m = 0; m < 4; ++m)
#pragma unroll
        for (int n = 0; n < 4; ++n)
            acc[m][n] = f32x4{0.f, 0.f, 0.f, 0.f};

    const int sr = tid >> 1;            // staging row 0..127
    const int sc = (tid & 1) * 16;      // staging col 0 / 16

    for (int k0 = 0; k0 < K; k0 += 32) {
        __syncthreads();
        {
            const float* Ap = &A[(size_t)(bm + sr) * K + k0 + sc];
            const float* Wp = &W[(size_t)(bn + sr) * K + k0 + sc];
            float4 a[4], b[4];
#pragma unroll
            for (int i = 0; i < 4; ++i) a[i] = *(const float4*)&Ap[4*i];
#pragma unroll
            for (int i = 0; i < 4; ++i) b[i] = *(const float4*)&Wp[4*i];
            uint4 u0 = {pack2bf(a[0].x,a[0].y), pack2bf(a[0].z,a[0].w),
                        pack2bf(a[1].x,a[1].y), pack2bf(a[1].z,a[1].w)};
            uint4 u1 = {pack2bf(a[2].x,a[2].y), pack2bf(a[2].z,a[2].w),
                        pack2bf(a[3].x,a[3].y), pack2bf(a[3].z,a[3].w)};
            *(uint4*)&As[sr][sc]     = u0;
            *(uint4*)&As[sr][sc + 8] = u1;
            uint4 v0 = {pack2bf(b[0].x,b[0].y), pack2bf(b[0].z,b[0].w),
                        pack2bf(b[1].x,b[1].y), pack2bf(b[1].z,b[1].w)};
            uint4 v1 = {pack2bf(b[2].x,b[2].y), pack2bf(b[2].z,b[2].w),
                        pack2bf(b[3].x,b[3].y), pack2bf(b[3].z,b[3].w)};
            *(uint4*)&Ws[sr][sc]     = v0;
            *(uint4*)&Ws[sr][sc + 8] = v1;
        }
        __syncthreads();

        bf16x8 af[4], wf[4];
#pragma unroll
        for (int i = 0; i < 4; ++i) {
            af[i] = ldfrag8(&As[0][0], wm + 16*i + lr, 8*lg);
            wf[i] = ldfrag8(&Ws[0][0], wn + 16*i + lr, 8*lg);
        }
#pragma unroll
        for (int m = 0; m < 4; ++m)
#pragma unroll
            for (int n = 0; n < 4; ++n)
                acc[m][n] = MFMA16(af[m], wf[n], acc[m][n]);
    }

    // D-layout: value(lane,reg) of subtile (msub,nsub) ->
    // C[bm+wm+16*msub+4*lg+reg][bn+wn+16*nsub+lr]
#pragma unroll
    for (int nsub = 0; nsub < 4; ++nsub) {
        const int n0 = bn + wn + 16*nsub + lr;
        const float bv = bias[n0];
#pragma unroll
        for (int msub = 0; msub < 4; ++msub) {
#pragma unroll
            for (int reg = 0; reg < 4; ++reg) {
                const int m = bm + wm + 16*msub + 4*lg + reg;
                float v = acc[msub][nsub][reg] + bv;
                if (MODE == 0) {
                    const int which = n0 >> 10;
                    const int e0 = n0 & 1023;
                    const int h = e0 >> 6, d0 = e0 & 63;
                    if (which == 0) v *= 0.125f;
                    float* dst = (which == 0) ? qbuf : (which == 1) ? kbuf : vbuf;
                    dst[((size_t)((m & 1)*Hh + h) * Tt + (m >> 1)) * HD + d0] = v;
                } else {
                    Cout[(size_t)m * N + n0] = v;
                }
            }
        }
    }
}

// ---------------------------------------------------------------------------
// MFMA fused attention. Block = (bh, 128-row Q-tile), 4 waves.
// QK^T swapped (S^T = mfma(K,Q)), contiguous-8 slots, b128 fragment reads.
// PV: P from registers (forced split slots), V via 2x b64.
// ---------------------------------------------------------------------------
__global__ __launch_bounds__(256)
void attn_mfma(const float* __restrict__ qb, const float* __restrict__ kb,
               const float* __restrict__ vb, const float* __restrict__ mask,
               float* __restrict__ attn, float* __restrict__ lbuf)
{
    __shared__ __align__(16) unsigned short Ks[64][72];   // K tile [s][d] (also Q staging)
    __shared__ __align__(16) unsigned short Vt[64][72];   // V tile transposed [d][s]
    __shared__ float l_sh[128];

    const int tid  = threadIdx.x;
    const int bh   = blockIdx.x;           // b*16+h
    const int t0   = blockIdx.y * 128;
    const int w    = tid >> 6;             // wave 0..3
    const int lane = tid & 63;
    const int lr   = lane & 15;
    const int lg   = lane >> 4;            // k-group 0..3
    const int b = bh >> 4, h = bh & 15;

    const float* __restrict__ Qg = qb + (size_t)bh * Tt * HD;
    const float* __restrict__ Kg = kb + (size_t)bh * Tt * HD;
    const float* __restrict__ Vg = vb + (size_t)bh * Tt * HD;

    // ---- Q fragments to registers (B-operand of swapped QK^T) ----
    bf16x8 qf[2][2];   // [u: 16-row subtile][d-half]
    for (int half = 0; half < 2; ++half) {
        __syncthreads();
#pragma unroll
        for (int p = 0; p < 4; ++p) {
            const int fidx = p*256 + tid;
            const int r = fidx >> 4, c4 = (fidx & 15) * 4;
            const float4 v = *(const float4*)&Qg[(size_t)(t0 + half*64 + r) * HD + c4];
            const uint2 u = {pack2bf(v.x, v.y), pack2bf(v.z, v.w)};
            *(uint2*)&Ks[r][c4] = u;
        }
        __syncthreads();
        if ((w >> 1) == half) {
#pragma unroll
            for (int u = 0; u < 2; ++u) {
                const int r = 32*(w & 1) + 16*u + lr;
                qf[u][0] = ldfrag8(&Ks[0][0], r, 8*lg);        // d 0..31
                qf[u][1] = ldfrag8(&Ks[0][0], r, 32 + 8*lg);   // d 32..63
            }
        }
    }

    f32x4 oacc[2][4];
#pragma unroll
    for (int u = 0; u < 2; ++u)
#pragma unroll
        for (int d = 0; d < 4; ++d)
            oacc[u][d] = f32x4{0.f, 0.f, 0.f, 0.f};
    float lacc[2] = {0.f, 0.f};

    for (int s0 = 0; s0 < Tt; s0 += 64) {
        __syncthreads();   // previous tile's fragment reads complete
#pragma unroll
        for (int p = 0; p < 4; ++p) {
            const int fidx = p*256 + tid;
            const int r = fidx >> 4, c4 = (fidx & 15) * 4;
            const float4 kv = *(const float4*)&Kg[(size_t)(s0 + r) * HD + c4];
            const uint2 u = {pack2bf(kv.x, kv.y), pack2bf(kv.z, kv.w)};
            *(uint2*)&Ks[r][c4] = u;
        }
#pragma unroll
        for (int p = 0; p < 2; ++p) {
            const int fidx = p*256 + tid;
            const int dg = fidx & 15, s2 = fidx >> 4;      // s2: 0..31
            const float4 a = *(const float4*)&Vg[(size_t)(s0 + 2*s2)     * HD + dg*4];
            const float4 c = *(const float4*)&Vg[(size_t)(s0 + 2*s2 + 1) * HD + dg*4];
            *(unsigned int*)&Vt[dg*4+0][2*s2] = pack2bf(a.x, c.x);
            *(unsigned int*)&Vt[dg*4+1][2*s2] = pack2bf(a.y, c.y);
            *(unsigned int*)&Vt[dg*4+2][2*s2] = pack2bf(a.z, c.z);
            *(unsigned int*)&Vt[dg*4+3][2*s2] = pack2bf(a.w, c.w);
        }
        __syncthreads();

        // QK^T (swapped): sacc[u][ssub] = S^T 16x16 tile (row=s, col=t)
        f32x4 sacc[2][4];
#pragma unroll
        for (int ssub = 0; ssub < 4; ++ssub) {
            const bf16x8 a0 = ldfrag8(&Ks[0][0], 16*ssub + lr, 8*lg);
            const bf16x8 a1 = ldfrag8(&Ks[0][0], 16*ssub + lr, 32 + 8*lg);
#pragma unroll
            for (int u = 0; u < 2; ++u) {
                f32x4 z = {0.f, 0.f, 0.f, 0.f};
                z = MFMA16(a0, qf[u][0], z);
                z = MFMA16(a1, qf[u][1], z);
                sacc[u][ssub] = z;
            }
        }

        // exp(score + mask): P packed straight into PV A-fragments; l partial
        unsigned int pw[2][8];
#pragma unroll
        for (int u = 0; u < 2; ++u) {
            float lt = 0.f;
            const float* __restrict__ mrow =
                &mask[(size_t)(t0 + 32*w + 16*u + lr) * Tt + s0];
#pragma unroll
            for (int ssub = 0; ssub < 4; ++ssub) {
                const float4 mv = *(const float4*)&mrow[16*ssub + 4*lg];
                const float e0 = __expf(sacc[u][ssub][0] + mv.x);
                const float e1 = __expf(sacc[u][ssub][1] + mv.y);
                const float e2 = __expf(sacc[u][ssub][2] + mv.z);
                const float e3 = __expf(sacc[u][ssub][3] + mv.w);
                lt += (e0 + e1) + (e2 + e3);
                pw[u][ssub*2]     = pack2bf(e0, e1);
                pw[u][ssub*2 + 1] = pack2bf(e2, e3);
            }
            lt += __shfl_xor(lt, 16);
            lt += __shfl_xor(lt, 32);
            lacc[u] += lt;
        }

        // PV: O[t][d] += P * V
#pragma unroll
        for (int dsub = 0; dsub < 4; ++dsub) {
            const bf16x8 b0 = ldfragV(&Vt[0][0], 16*dsub + lr, 4*lg);
            const bf16x8 b1 = ldfragV(&Vt[0][0], 16*dsub + lr, 32 + 4*lg);
#pragma unroll
            for (int u = 0; u < 2; ++u) {
                const uint4 ua = {pw[u][0], pw[u][1], pw[u][2], pw[u][3]};
                const uint4 ub = {pw[u][4], pw[u][5], pw[u][6], pw[u][7]};
                oacc[u][dsub] = MFMA16(__builtin_bit_cast(bf16x8, ua), b0, oacc[u][dsub]);
                oacc[u][dsub] = MFMA16(__builtin_bit_cast(bf16x8, ub), b1, oacc[u][dsub]);
            }
        }
    }

    __syncthreads();
    if (lg == 0) {
        l_sh[32*w + lr]      = lacc[0];
        l_sh[32*w + 16 + lr] = lacc[1];
    }
    __syncthreads();
#pragma unroll
    for (int u = 0; u < 2; ++u) {
#pragma unroll
        for (int reg = 0; reg < 4; ++reg) {
            const int tl = 32*w + 16*u + 4*lg + reg;
            const float inv = 1.f / l_sh[tl];
            const int t = t0 + tl;
#pragma unroll
            for (int dsub = 0; dsub < 4; ++dsub)
                attn[((size_t)t * Bb + b) * Ee + h*HD + dsub*16 + lr] =
                    oacc[u][dsub][reg] * inv;
        }
        if (lg == 0)
            lbuf[(size_t)bh * Tt + t0 + 32*w + 16*u + lr] = lacc[u];
    }
}

// ---------------------------------------------------------------------------
// MFMA avg_w pass: block = (b, 64 t-rows, 64 s-cols); loops 16 heads.
// ---------------------------------------------------------------------------
__global__ __launch_bounds__(256)
void avg_probs_mfma(const float* __restrict__ qb, const float* __restrict__ kb,
                    const float* __restrict__ mask, const float* __restrict__ lbuf,
                    float* __restrict__ avg)
{
    __shared__ __align__(16) unsigned short Qs[64][72];
    __shared__ __align__(16) unsigned short Ksh[64][72];
    __shared__ float linv[16][64];

    const int tid  = threadIdx.x;
    const int b    = blockIdx.z;
    const int t0   = blockIdx.y * 64;
    const int s0   = blockIdx.x * 64;
    const int w    = tid >> 6;
    const int lane = tid & 63;
    const int lr   = lane & 15;
    const int lg   = lane >> 4;

    {   // stage 1/(16*l) for all 16 heads of this t-tile
        const int h = tid >> 4, tl = (tid & 15) * 4;
        const float4 lv = *(const float4*)&lbuf[(size_t)(b*Hh + h) * Tt + t0 + tl];
        linv[h][tl+0] = 1.f / (16.f * lv.x);
        linv[h][tl+1] = 1.f / (16.f * lv.y);
        linv[h][tl+2] = 1.f / (16.f * lv.z);
        linv[h][tl+3] = 1.f / (16.f * lv.w);
    }

    // mask fragments (value(lane,reg) at t=t0+16w+4lg+reg, s=s0+16ssub+lr)
    f32x4 mf[4];
#pragma unroll
    for (int ssub = 0; ssub < 4; ++ssub)
#pragma unroll
        for (int reg = 0; reg < 4; ++reg)
            mf[ssub][reg] = mask[(size_t)(t0 + 16*w + 4*lg + reg) * Tt + s0 + 16*ssub + lr];

    f32x4 av[4];
#pragma unroll
    for (int ssub = 0; ssub < 4; ++ssub) av[ssub] = f32x4{0.f, 0.f, 0.f, 0.f};

    for (int h = 0; h < Hh; ++h) {
        const float* __restrict__ Qg = qb + (size_t)(b*Hh + h) * Tt * HD;
        const float* __restrict__ Kg = kb + (size_t)(b*Hh + h) * Tt * HD;
        __syncthreads();   // prev iter fragment reads done (h=0: orders linv too)
        {
            const int r = tid >> 2, c0 = (tid & 3) * 16;
            const float* Qp = &Qg[(size_t)(t0 + r) * HD + c0];
            const float* Kp = &Kg[(size_t)(s0 + r) * HD + c0];
            float4 a[4], k[4];
#pragma unroll
            for (int i = 0; i < 4; ++i) a[i] = *(const float4*)&Qp[4*i];
#pragma unroll
            for (int i = 0; i < 4; ++i) k[i] = *(const float4*)&Kp[4*i];
            uint4 u0 = {pack2bf(a[0].x,a[0].y), pack2bf(a[0].z,a[0].w),
                        pack2bf(a[1].x,a[1].y), pack2bf(a[1].z,a[1].w)};
            uint4 u1 = {pack2bf(a[2].x,a[2].y), pack2bf(a[2].z,a[2].w),
                        pack2bf(a[3].x,a[3].y), pack2bf(a[3].z,a[3].w)};
            *(uint4*)&Qs[r][c0]     = u0;
            *(uint4*)&Qs[r][c0 + 8] = u1;
            uint4 v0 = {pack2bf(k[0].x,k[0].y), pack2bf(k[0].z,k[0].w),
                        pack2bf(k[1].x,k[1].y), pack2bf(k[1].z,k[1].w)};
            uint4 v1 = {pack2bf(k[2].x,k[2].y), pack2bf(k[2].z,k[2].w),
                        pack2bf(k[3].x,k[3].y), pack2bf(k[3].z,k[3].w)};
            *(uint4*)&Ksh[r][c0]     = v0;
            *(uint4*)&Ksh[r][c0 + 8] = v1;
        }
        __syncthreads();

        const float lv0 = linv[h][16*w + 4*lg + 0];
        const float lv1 = linv[h][16*w + 4*lg + 1];
        const float lv2 = linv[h][16*w + 4*lg + 2];
        const float lv3 = linv[h][16*w + 4*lg + 3];

        const bf16x8 af0 = ldfrag8(&Qs[0][0], 16*w + lr, 8*lg);
        const bf16x8 af1 = ldfrag8(&Qs[0][0], 16*w + lr, 32 + 8*lg);
#pragma unroll
        for (int ssub = 0; ssub < 4; ++ssub) {
            const bf16x8 bf0 = ldfrag8(&Ksh[0][0], 16*ssub + lr, 8*lg);
            const bf16x8 bf1 = ldfrag8(&Ksh[0][0], 16*ssub + lr, 32 + 8*lg);
            f32x4 z = {0.f, 0.f, 0.f, 0.f};
            z = MFMA16(af0, bf0, z);
            z = MFMA16(af1, bf1, z);
            av[ssub][0] += __expf(z[0] + mf[ssub][0]) * lv0;
            av[ssub][1] += __expf(z[1] + mf[ssub][1]) * lv1;
            av[ssub][2] += __expf(z[2] + mf[ssub][2]) * lv2;
            av[ssub][3] += __expf(z[3] + mf[ssub][3]) * lv3;
        }
    }

#pragma unroll
    for (int ssub = 0; ssub < 4; ++ssub)
#pragma unroll
        for (int reg = 0; reg < 4; ++reg)
            avg[((size_t)b * Tt + t0 + 16*w + 4*lg + reg) * Tt + s0 + 16*ssub + lr] =
                av[ssub][reg];
}

// ---------------------------------------------------------------------------
extern "C" void kernel_launch(void* const* d_in, const int* in_sizes, int n_in,
                              void* d_out, int out_size, void* d_ws, size_t ws_size,
                              hipStream_t stream)
{
    (void)in_sizes; (void)n_in; (void)out_size; (void)ws_size;
    const float* query = (const float*)d_in[0];   // [T,B,E]
    const float* mask  = (const float*)d_in[1];   // [T,T]
    const float* Wqkv  = (const float*)d_in[2];   // [3E,E]
    const float* bqkv  = (const float*)d_in[3];   // [3E]
    const float* Wout  = (const float*)d_in[4];   // [E,E]
    const float* bout  = (const float*)d_in[5];   // [E]

    float* out = (float*)d_out;                   // [T,B,E]
    float* avg = out + (size_t)Tt * Bb * Ee;      // [B,T,T]

    float* ws   = (float*)d_ws;
    float* qbuf = ws;                                 // [B*H][T][hd] (pre-scaled)
    float* kbuf = qbuf + (size_t)BHh * Tt * HD;
    float* vbuf = kbuf + (size_t)BHh * Tt * HD;
    float* attn = vbuf + (size_t)BHh * Tt * HD;       // [T,B,E]
    float* lbuf = attn + (size_t)Mm * Ee;             // [B*H][T]

    // 1) fused QKV projection (MFMA; scatter to head-major, scale Q)
    gemm_mfma<0><<<dim3(3072/128, Mm/128), 256, 0, stream>>>(
        query, Wqkv, bqkv, nullptr, qbuf, kbuf, vbuf, 3072, Ee);
    // 2) MFMA fused attention (l + PV)
    attn_mfma<<<dim3(BHh, Tt/128), 256, 0, stream>>>(
        qbuf, kbuf, vbuf, mask, attn, lbuf);
    // 3) head-averaged probs (MFMA)
    avg_probs_mfma<<<dim3(Tt/64, Tt/64, Bb), 256, 0, stream>>>(
        qbuf, kbuf, mask, lbuf, avg);
    // 4) output projection (MFMA)
    gemm_mfma<1><<<dim3(Ee/128, Mm/128), 256, 0, stream>>>(
        attn, Wout, bout, out, nullptr, nullptr, nullptr, Ee, Ee);
}

// Round 10
// 250.066 us; speedup vs baseline: 1.3065x; 1.3065x over previous
//
#include <hip/hip_runtime.h>
#include <cstdint>
#include <cstddef>

#define Tt 2048
#define Bb 2
#define Ee 1024
#define Hh 16
#define HD 64
#define BHh (Bb*Hh)
#define Mm (Tt*Bb)

typedef short bf16x8 __attribute__((ext_vector_type(8)));
typedef float f32x4  __attribute__((ext_vector_type(4)));

#define MFMA16(a,b,c) __builtin_amdgcn_mfma_f32_16x16x32_bf16(a, b, c, 0, 0, 0)

// Software RNE f32->bf16 (R7-validated; inline-asm v_cvt_pk_bf16_f32 is WRONG
// on this path — R8 failed with truncation-bias-magnitude error 1e-2).
__device__ __forceinline__ unsigned short f2bf(float f) {
    unsigned int u = __builtin_bit_cast(unsigned int, f);
    u += 0x7FFFu + ((u >> 16) & 1u);        // RNE
    return (unsigned short)(u >> 16);
}
__device__ __forceinline__ unsigned int pack2bf(float lo, float hi) {
    return (unsigned int)f2bf(lo) | ((unsigned int)f2bf(hi) << 16);
}

// R7-proven LDS fragment load, pitch 66 ushorts. Split k-slot convention:
// slot j<4 -> col+j, j>=4 -> col+16+(j-4). Same map used by both MFMA
// operands everywhere (+ forced P/V pairing) -> permutation-consistent.
__device__ __forceinline__ bf16x8 ldfrag(const unsigned short* base, int row, int col) {
    const unsigned int* p = (const unsigned int*)(base + row*66 + col);
    const unsigned int* q = (const unsigned int*)(base + row*66 + col + 16);
    uint4 u;
    u.x = p[0]; u.y = p[1];
    u.z = q[0]; u.w = q[1];
    return __builtin_bit_cast(bf16x8, u);
}

// ---------------------------------------------------------------------------
// f32 -> bf16 prepack (RNE), vectorized x8. n8 = n/8.
// ---------------------------------------------------------------------------
__global__ __launch_bounds__(256)
void to_bf16(const float* __restrict__ src, unsigned short* __restrict__ dst, int n8)
{
    const int stride = gridDim.x * 256;
    for (int i = blockIdx.x*256 + threadIdx.x; i < n8; i += stride) {
        const float4 a = ((const float4*)src)[2*i];
        const float4 b = ((const float4*)src)[2*i + 1];
        const uint4 u = {pack2bf(a.x,a.y), pack2bf(a.z,a.w),
                         pack2bf(b.x,b.y), pack2bf(b.z,b.w)};
        ((uint4*)dst)[i] = u;
    }
}

// ---------------------------------------------------------------------------
// MFMA GEMM on bf16 inputs: C[M,N] = A[M,K]*W[N,K]^T + bias[N].
// 128x128 tile, BK=32, 4 waves (2x2), wave = 64x64 out. R7 LDS machinery.
// MODE 0: scatter bf16 into head-major Q/K/V (scale Q by 0.125).
// MODE 1: f32 store to Cout.
// ---------------------------------------------------------------------------
template<int MODE>
__global__ __launch_bounds__(256)
void gemm_mfma(const unsigned short* __restrict__ A, const unsigned short* __restrict__ W,
               const float* __restrict__ bias, float* __restrict__ Cout,
               unsigned short* __restrict__ qbuf, unsigned short* __restrict__ kbuf,
               unsigned short* __restrict__ vbuf, int N, int K)
{
    __shared__ unsigned short As[128][66];
    __shared__ unsigned short Ws[128][66];
    const int tid  = threadIdx.x;
    const int bm   = blockIdx.y * 128;
    const int bn   = blockIdx.x * 128;
    const int w    = tid >> 6;
    const int lane = tid & 63;
    const int lr   = lane & 15;
    const int lg   = lane >> 4;
    const int wm   = (w >> 1) * 64;
    const int wn   = (w & 1) * 64;

    f32x4 acc[4][4];
#pragma unroll
    for (int m = 0; m < 4; ++m)
#pragma unroll
        for (int n = 0; n < 4; ++n)
            acc[m][n] = f32x4{0.f, 0.f, 0.f, 0.f};

    const int sr = tid >> 1;            // staging row 0..127
    const int sc = (tid & 1) * 16;      // staging col 0 / 16 (ushorts)

    for (int k0 = 0; k0 < K; k0 += 32) {
        __syncthreads();
        {
            const unsigned short* Ap = &A[(size_t)(bm + sr) * K + k0 + sc];
            const unsigned short* Wp = &W[(size_t)(bn + sr) * K + k0 + sc];
            const uint4 a0 = *(const uint4*)Ap;
            const uint4 a1 = *(const uint4*)(Ap + 8);
            const uint4 w0 = *(const uint4*)Wp;
            const uint4 w1 = *(const uint4*)(Wp + 8);
            *(uint4*)&As[sr][sc]     = a0;
            *(uint4*)&As[sr][sc + 8] = a1;
            *(uint4*)&Ws[sr][sc]     = w0;
            *(uint4*)&Ws[sr][sc + 8] = w1;
        }
        __syncthreads();

        bf16x8 af[4], wf[4];
#pragma unroll
        for (int i = 0; i < 4; ++i) {
            af[i] = ldfrag(&As[0][0], wm + 16*i + lr, 4*lg);
            wf[i] = ldfrag(&Ws[0][0], wn + 16*i + lr, 4*lg);
        }
#pragma unroll
        for (int m = 0; m < 4; ++m)
#pragma unroll
            for (int n = 0; n < 4; ++n)
                acc[m][n] = MFMA16(af[m], wf[n], acc[m][n]);
    }

    // D-layout: value(lane,reg) of subtile (msub,nsub) ->
    // C[bm+wm+16*msub+4*lg+reg][bn+wn+16*nsub+lr]
#pragma unroll
    for (int nsub = 0; nsub < 4; ++nsub) {
        const int n0 = bn + wn + 16*nsub + lr;
        const float bv = bias[n0];
#pragma unroll
        for (int msub = 0; msub < 4; ++msub) {
#pragma unroll
            for (int reg = 0; reg < 4; ++reg) {
                const int m = bm + wm + 16*msub + 4*lg + reg;
                float v = acc[msub][nsub][reg] + bv;
                if (MODE == 0) {
                    const int which = n0 >> 10;
                    const int e0 = n0 & 1023;
                    const int h = e0 >> 6, d0 = e0 & 63;
                    if (which == 0) v *= 0.125f;
                    unsigned short* dst = (which == 0) ? qbuf : (which == 1) ? kbuf : vbuf;
                    dst[((size_t)((m & 1)*Hh + h) * Tt + (m >> 1)) * HD + d0] = f2bf(v);
                } else {
                    Cout[(size_t)m * N + n0] = v;
                }
            }
        }
    }
}

// ---------------------------------------------------------------------------
// MFMA fused attention, bf16 Q/K/V in, bf16 attn out (+ f32 l).
// Block = (bh, 128-row Q-tile), 4 waves. R7 LDS machinery (pitch 66).
// ---------------------------------------------------------------------------
__global__ __launch_bounds__(256)
void attn_mfma(const unsigned short* __restrict__ qb, const unsigned short* __restrict__ kb,
               const unsigned short* __restrict__ vb, const float* __restrict__ mask,
               unsigned short* __restrict__ attnb, float* __restrict__ lbuf)
{
    __shared__ unsigned short Ks[64][66];   // K tile [s][d] (also Q staging)
    __shared__ unsigned short Vt[64][66];   // V tile transposed [d][s-pairs]
    __shared__ float l_sh[128];

    const int tid  = threadIdx.x;
    const int bh   = blockIdx.x;           // b*16+h
    const int t0   = blockIdx.y * 128;
    const int w    = tid >> 6;             // wave 0..3
    const int lane = tid & 63;
    const int lr   = lane & 15;
    const int lg   = lane >> 4;            // k-group 0..3
    const int b = bh >> 4, h = bh & 15;

    const unsigned short* __restrict__ Qg = qb + (size_t)bh * Tt * HD;
    const unsigned short* __restrict__ Kg = kb + (size_t)bh * Tt * HD;
    const unsigned short* __restrict__ Vg = vb + (size_t)bh * Tt * HD;

    const int str = tid >> 2;              // staging row 0..63
    const int stc = (tid & 3) * 16;        // staging col (ushorts)

    // ---- Q fragments to registers (B-operand of swapped QK^T) ----
    bf16x8 qf[2][2];   // [u: 16-row subtile][d-half]
    for (int half = 0; half < 2; ++half) {
        __syncthreads();
        {
            const unsigned short* Qp = &Qg[(size_t)(t0 + half*64 + str) * HD + stc];
            const uint4 u0 = *(const uint4*)Qp;
            const uint4 u1 = *(const uint4*)(Qp + 8);
            *(uint4*)&Ks[str][stc]     = u0;
            *(uint4*)&Ks[str][stc + 8] = u1;
        }
        __syncthreads();
        if ((w >> 1) == half) {
#pragma unroll
            for (int u = 0; u < 2; ++u) {
                const int r = 32*(w & 1) + 16*u + lr;
                qf[u][0] = ldfrag(&Ks[0][0], r, 4*lg);        // d 0..31
                qf[u][1] = ldfrag(&Ks[0][0], r, 32 + 4*lg);   // d 32..63
            }
        }
    }

    f32x4 oacc[2][4];
#pragma unroll
    for (int u = 0; u < 2; ++u)
#pragma unroll
        for (int d = 0; d < 4; ++d)
            oacc[u][d] = f32x4{0.f, 0.f, 0.f, 0.f};
    float lacc[2] = {0.f, 0.f};

    for (int s0 = 0; s0 < Tt; s0 += 64) {
        __syncthreads();   // previous tile's fragment reads complete
        {   // stage K (row-major copy)
            const unsigned short* Kp = &Kg[(size_t)(s0 + str) * HD + stc];
            const uint4 u0 = *(const uint4*)Kp;
            const uint4 u1 = *(const uint4*)(Kp + 8);
            *(uint4*)&Ks[str][stc]     = u0;
            *(uint4*)&Ks[str][stc + 8] = u1;
        }
#pragma unroll
        for (int p = 0; p < 2; ++p) {   // stage V transposed via halfword ops
            const int fidx = p*256 + tid;
            const int dg = fidx & 15, s2 = fidx >> 4;      // s2: 0..31
            const uint2 a = *(const uint2*)&Vg[(size_t)(s0 + 2*s2)     * HD + dg*4];
            const uint2 c = *(const uint2*)&Vg[(size_t)(s0 + 2*s2 + 1) * HD + dg*4];
            *(unsigned int*)&Vt[dg*4+0][2*s2] = (a.x & 0xFFFFu) | (c.x << 16);
            *(unsigned int*)&Vt[dg*4+1][2*s2] = (a.x >> 16)     | (c.x & 0xFFFF0000u);
            *(unsigned int*)&Vt[dg*4+2][2*s2] = (a.y & 0xFFFFu) | (c.y << 16);
            *(unsigned int*)&Vt[dg*4+3][2*s2] = (a.y >> 16)     | (c.y & 0xFFFF0000u);
        }
        __syncthreads();

        // QK^T (swapped): sacc[u][ssub] = S^T 16x16 tile (row=s, col=t)
        f32x4 sacc[2][4];
#pragma unroll
        for (int ssub = 0; ssub < 4; ++ssub) {
            const bf16x8 a0 = ldfrag(&Ks[0][0], 16*ssub + lr, 4*lg);
            const bf16x8 a1 = ldfrag(&Ks[0][0], 16*ssub + lr, 32 + 4*lg);
#pragma unroll
            for (int u = 0; u < 2; ++u) {
                f32x4 z = {0.f, 0.f, 0.f, 0.f};
                z = MFMA16(a0, qf[u][0], z);
                z = MFMA16(a1, qf[u][1], z);
                sacc[u][ssub] = z;
            }
        }

        // exp(score + mask): P packed into PV A-fragments; l partial
        unsigned int pw[2][8];
#pragma unroll
        for (int u = 0; u < 2; ++u) {
            float lt = 0.f;
            const float* __restrict__ mrow =
                &mask[(size_t)(t0 + 32*w + 16*u + lr) * Tt + s0];
#pragma unroll
            for (int ssub = 0; ssub < 4; ++ssub) {
                const float4 mv = *(const float4*)&mrow[16*ssub + 4*lg];
                const float e0 = __expf(sacc[u][ssub][0] + mv.x);
                const float e1 = __expf(sacc[u][ssub][1] + mv.y);
                const float e2 = __expf(sacc[u][ssub][2] + mv.z);
                const float e3 = __expf(sacc[u][ssub][3] + mv.w);
                lt += (e0 + e1) + (e2 + e3);
                pw[u][ssub*2]     = pack2bf(e0, e1);
                pw[u][ssub*2 + 1] = pack2bf(e2, e3);
            }
            lt += __shfl_xor(lt, 16);
            lt += __shfl_xor(lt, 32);
            lacc[u] += lt;
        }

        // PV: O[t][d] += P * V
#pragma unroll
        for (int dsub = 0; dsub < 4; ++dsub) {
            const bf16x8 b0 = ldfrag(&Vt[0][0], 16*dsub + lr, 4*lg);
            const bf16x8 b1 = ldfrag(&Vt[0][0], 16*dsub + lr, 32 + 4*lg);
#pragma unroll
            for (int u = 0; u < 2; ++u) {
                const uint4 ua = {pw[u][0], pw[u][1], pw[u][2], pw[u][3]};
                const uint4 ub = {pw[u][4], pw[u][5], pw[u][6], pw[u][7]};
                oacc[u][dsub] = MFMA16(__builtin_bit_cast(bf16x8, ua), b0, oacc[u][dsub]);
                oacc[u][dsub] = MFMA16(__builtin_bit_cast(bf16x8, ub), b1, oacc[u][dsub]);
            }
        }
    }

    __syncthreads();
    if (lg == 0) {
        l_sh[32*w + lr]      = lacc[0];
        l_sh[32*w + 16 + lr] = lacc[1];
    }
    __syncthreads();
#pragma unroll
    for (int u = 0; u < 2; ++u) {
#pragma unroll
        for (int reg = 0; reg < 4; ++reg) {
            const int tl = 32*w + 16*u + 4*lg + reg;
            const float inv = 1.f / l_sh[tl];
            const int t = t0 + tl;
#pragma unroll
            for (int dsub = 0; dsub < 4; ++dsub)
                attnb[((size_t)t * Bb + b) * Ee + h*HD + dsub*16 + lr] =
                    f2bf(oacc[u][dsub][reg] * inv);
        }
        if (lg == 0)
            lbuf[(size_t)bh * Tt + t0 + 32*w + 16*u + lr] = lacc[u];
    }
}

// ---------------------------------------------------------------------------
// MFMA avg_w pass (bf16 Q/K in): block = (b, 64 t, 64 s); loops 16 heads.
// ---------------------------------------------------------------------------
__global__ __launch_bounds__(256)
void avg_probs_mfma(const unsigned short* __restrict__ qb, const unsigned short* __restrict__ kb,
                    const float* __restrict__ mask, const float* __restrict__ lbuf,
                    float* __restrict__ avg)
{
    __shared__ unsigned short Qs[64][66];
    __shared__ unsigned short Ksh[64][66];
    __shared__ float linv[16][64];

    const int tid  = threadIdx.x;
    const int b    = blockIdx.z;
    const int t0   = blockIdx.y * 64;
    const int s0   = blockIdx.x * 64;
    const int w    = tid >> 6;
    const int lane = tid & 63;
    const int lr   = lane & 15;
    const int lg   = lane >> 4;

    {   // stage 1/(16*l) for all 16 heads of this t-tile
        const int h = tid >> 4, tl = (tid & 15) * 4;
        const float4 lv = *(const float4*)&lbuf[(size_t)(b*Hh + h) * Tt + t0 + tl];
        linv[h][tl+0] = 1.f / (16.f * lv.x);
        linv[h][tl+1] = 1.f / (16.f * lv.y);
        linv[h][tl+2] = 1.f / (16.f * lv.z);
        linv[h][tl+3] = 1.f / (16.f * lv.w);
    }

    // mask fragments (value(lane,reg) at t=t0+16w+4lg+reg, s=s0+16ssub+lr)
    f32x4 mf[4];
#pragma unroll
    for (int ssub = 0; ssub < 4; ++ssub)
#pragma unroll
        for (int reg = 0; reg < 4; ++reg)
            mf[ssub][reg] = mask[(size_t)(t0 + 16*w + 4*lg + reg) * Tt + s0 + 16*ssub + lr];

    f32x4 av[4];
#pragma unroll
    for (int ssub = 0; ssub < 4; ++ssub) av[ssub] = f32x4{0.f, 0.f, 0.f, 0.f};

    const int str = tid >> 2;              // staging row 0..63
    const int stc = (tid & 3) * 16;        // staging col (ushorts)

    for (int h = 0; h < Hh; ++h) {
        const unsigned short* __restrict__ Qg = qb + (size_t)(b*Hh + h) * Tt * HD;
        const unsigned short* __restrict__ Kg = kb + (size_t)(b*Hh + h) * Tt * HD;
        __syncthreads();   // prev iter fragment reads done (h=0: orders linv too)
        {
            const unsigned short* Qp = &Qg[(size_t)(t0 + str) * HD + stc];
            const unsigned short* Kp = &Kg[(size_t)(s0 + str) * HD + stc];
            const uint4 q0 = *(const uint4*)Qp;
            const uint4 q1 = *(const uint4*)(Qp + 8);
            const uint4 k0 = *(const uint4*)Kp;
            const uint4 k1 = *(const uint4*)(Kp + 8);
            *(uint4*)&Qs[str][stc]      = q0;
            *(uint4*)&Qs[str][stc + 8]  = q1;
            *(uint4*)&Ksh[str][stc]     = k0;
            *(uint4*)&Ksh[str][stc + 8] = k1;
        }
        __syncthreads();

        const float lv0 = linv[h][16*w + 4*lg + 0];
        const float lv1 = linv[h][16*w + 4*lg + 1];
        const float lv2 = linv[h][16*w + 4*lg + 2];
        const float lv3 = linv[h][16*w + 4*lg + 3];

        const bf16x8 af0 = ldfrag(&Qs[0][0], 16*w + lr, 4*lg);
        const bf16x8 af1 = ldfrag(&Qs[0][0], 16*w + lr, 32 + 4*lg);
#pragma unroll
        for (int ssub = 0; ssub < 4; ++ssub) {
            const bf16x8 bf0 = ldfrag(&Ksh[0][0], 16*ssub + lr, 4*lg);
            const bf16x8 bf1 = ldfrag(&Ksh[0][0], 16*ssub + lr, 32 + 4*lg);
            f32x4 z = {0.f, 0.f, 0.f, 0.f};
            z = MFMA16(af0, bf0, z);
            z = MFMA16(af1, bf1, z);
            av[ssub][0] += __expf(z[0] + mf[ssub][0]) * lv0;
            av[ssub][1] += __expf(z[1] + mf[ssub][1]) * lv1;
            av[ssub][2] += __expf(z[2] + mf[ssub][2]) * lv2;
            av[ssub][3] += __expf(z[3] + mf[ssub][3]) * lv3;
        }
    }

#pragma unroll
    for (int ssub = 0; ssub < 4; ++ssub)
#pragma unroll
        for (int reg = 0; reg < 4; ++reg)
            avg[((size_t)b * Tt + t0 + 16*w + 4*lg + reg) * Tt + s0 + 16*ssub + lr] =
                av[ssub][reg];
}

// ---------------------------------------------------------------------------
extern "C" void kernel_launch(void* const* d_in, const int* in_sizes, int n_in,
                              void* d_out, int out_size, void* d_ws, size_t ws_size,
                              hipStream_t stream)
{
    (void)in_sizes; (void)n_in; (void)out_size; (void)ws_size;
    const float* query = (const float*)d_in[0];   // [T,B,E]
    const float* mask  = (const float*)d_in[1];   // [T,T]
    const float* Wqkv  = (const float*)d_in[2];   // [3E,E]
    const float* bqkv  = (const float*)d_in[3];   // [3E]
    const float* Wout  = (const float*)d_in[4];   // [E,E]
    const float* bout  = (const float*)d_in[5];   // [E]

    float* out = (float*)d_out;                   // [T,B,E]
    float* avg = out + (size_t)Tt * Bb * Ee;      // [B,T,T]

    const size_t S1 = (size_t)BHh * Tt * HD;      // 4,194,304
    unsigned short* wsu     = (unsigned short*)d_ws;
    unsigned short* qbuf    = wsu;                 // bf16, Q pre-scaled
    unsigned short* kbuf    = qbuf + S1;
    unsigned short* vbuf    = kbuf + S1;
    unsigned short* attnb   = vbuf + S1;           // bf16 [T*B][E]
    unsigned short* querybf = attnb + (size_t)Mm * Ee;
    unsigned short* wqkvbf  = querybf + (size_t)Mm * Ee;
    unsigned short* woutbf  = wqkvbf + (size_t)3 * Ee * Ee;
    float*          lbuf    = (float*)(woutbf + (size_t)Ee * Ee);

    // 0) prepack f32 weights/activations to bf16 (RNE; bit-identical to the
    //    rounding previously done inside the consumers)
    to_bf16<<<1024, 256, 0, stream>>>(query, querybf, (Mm*Ee)/8);
    to_bf16<<<1024, 256, 0, stream>>>(Wqkv, wqkvbf, (3*Ee*Ee)/8);
    to_bf16<<<512,  256, 0, stream>>>(Wout, woutbf, (Ee*Ee)/8);

    // 1) fused QKV projection (MFMA; scatter bf16 head-major, scale Q)
    gemm_mfma<0><<<dim3(3072/128, Mm/128), 256, 0, stream>>>(
        querybf, wqkvbf, bqkv, nullptr, qbuf, kbuf, vbuf, 3072, Ee);
    // 2) MFMA fused attention (l + PV), bf16 out
    attn_mfma<<<dim3(BHh, Tt/128), 256, 0, stream>>>(
        qbuf, kbuf, vbuf, mask, attnb, lbuf);
    // 3) head-averaged probs (MFMA)
    avg_probs_mfma<<<dim3(Tt/64, Tt/64, Bb), 256, 0, stream>>>(
        qbuf, kbuf, mask, lbuf, avg);
    // 4) output projection (MFMA)
    gemm_mfma<1><<<dim3(Ee/128, Mm/128), 256, 0, stream>>>(
        attnb, woutbf, bout, out, nullptr, nullptr, nullptr, Ee, Ee);
}

// Round 11
// 244.902 us; speedup vs baseline: 1.3341x; 1.0211x over previous
//
#include <hip/hip_runtime.h>
#include <cstdint>
#include <cstddef>

#define Tt 2048
#define Bb 2
#define Ee 1024
#define Hh 16
#define HD 64
#define BHh (Bb*Hh)
#define Mm (Tt*Bb)

typedef short bf16x8 __attribute__((ext_vector_type(8)));
typedef float f32x4  __attribute__((ext_vector_type(4)));

#define MFMA16(a,b,c) __builtin_amdgcn_mfma_f32_16x16x32_bf16(a, b, c, 0, 0, 0)

// Software RNE f32->bf16 (R7-validated; inline-asm v_cvt_pk_bf16_f32 is WRONG
// on this path — R8 failed with truncation-bias-magnitude error 1e-2).
__device__ __forceinline__ unsigned short f2bf(float f) {
    unsigned int u = __builtin_bit_cast(unsigned int, f);
    u += 0x7FFFu + ((u >> 16) & 1u);        // RNE
    return (unsigned short)(u >> 16);
}
__device__ __forceinline__ unsigned int pack2bf(float lo, float hi) {
    return (unsigned int)f2bf(lo) | ((unsigned int)f2bf(hi) << 16);
}

// R7-proven LDS fragment load, pitch 66 ushorts. Split k-slot convention:
// slot j<4 -> col+j, j>=4 -> col+16+(j-4). Same map used by both MFMA
// operands everywhere (+ forced P/V pairing) -> permutation-consistent.
__device__ __forceinline__ bf16x8 ldfrag(const unsigned short* base, int row, int col) {
    const unsigned int* p = (const unsigned int*)(base + row*66 + col);
    const unsigned int* q = (const unsigned int*)(base + row*66 + col + 16);
    uint4 u;
    u.x = p[0]; u.y = p[1];
    u.z = q[0]; u.w = q[1];
    return __builtin_bit_cast(bf16x8, u);
}

// ---------------------------------------------------------------------------
// f32 -> bf16 prepack (RNE), vectorized x8. n8 = n/8.
// ---------------------------------------------------------------------------
__global__ __launch_bounds__(256)
void to_bf16(const float* __restrict__ src, unsigned short* __restrict__ dst, int n8)
{
    const int stride = gridDim.x * 256;
    for (int i = blockIdx.x*256 + threadIdx.x; i < n8; i += stride) {
        const float4 a = ((const float4*)src)[2*i];
        const float4 b = ((const float4*)src)[2*i + 1];
        const uint4 u = {pack2bf(a.x,a.y), pack2bf(a.z,a.w),
                         pack2bf(b.x,b.y), pack2bf(b.z,b.w)};
        ((uint4*)dst)[i] = u;
    }
}

// ---------------------------------------------------------------------------
// MFMA GEMM on bf16 inputs: C[M,N] = A[M,K]*W[N,K]^T + bias[N].
// 128x128 tile, BK=32, 4 waves (2x2), wave = 64x64 out. R7 LDS machinery.
// MODE 0: scatter bf16 into head-major Q/K/V (scale Q by 0.125).
// MODE 1: f32 store to Cout.
// ---------------------------------------------------------------------------
template<int MODE>
__global__ __launch_bounds__(256)
void gemm_mfma(const unsigned short* __restrict__ A, const unsigned short* __restrict__ W,
               const float* __restrict__ bias, float* __restrict__ Cout,
               unsigned short* __restrict__ qbuf, unsigned short* __restrict__ kbuf,
               unsigned short* __restrict__ vbuf, int N, int K)
{
    __shared__ unsigned short As[128][66];
    __shared__ unsigned short Ws[128][66];
    const int tid  = threadIdx.x;
    const int bm   = blockIdx.y * 128;
    const int bn   = blockIdx.x * 128;
    const int w    = tid >> 6;
    const int lane = tid & 63;
    const int lr   = lane & 15;
    const int lg   = lane >> 4;
    const int wm   = (w >> 1) * 64;
    const int wn   = (w & 1) * 64;

    f32x4 acc[4][4];
#pragma unroll
    for (int m = 0; m < 4; ++m)
#pragma unroll
        for (int n = 0; n < 4; ++n)
            acc[m][n] = f32x4{0.f, 0.f, 0.f, 0.f};

    const int sr = tid >> 1;            // staging row 0..127
    const int sc = (tid & 1) * 16;      // staging col 0 / 16 (ushorts)

    for (int k0 = 0; k0 < K; k0 += 32) {
        __syncthreads();
        {
            const unsigned short* Ap = &A[(size_t)(bm + sr) * K + k0 + sc];
            const unsigned short* Wp = &W[(size_t)(bn + sr) * K + k0 + sc];
            const uint4 a0 = *(const uint4*)Ap;
            const uint4 a1 = *(const uint4*)(Ap + 8);
            const uint4 w0 = *(const uint4*)Wp;
            const uint4 w1 = *(const uint4*)(Wp + 8);
            *(uint4*)&As[sr][sc]     = a0;
            *(uint4*)&As[sr][sc + 8] = a1;
            *(uint4*)&Ws[sr][sc]     = w0;
            *(uint4*)&Ws[sr][sc + 8] = w1;
        }
        __syncthreads();

        bf16x8 af[4], wf[4];
#pragma unroll
        for (int i = 0; i < 4; ++i) {
            af[i] = ldfrag(&As[0][0], wm + 16*i + lr, 4*lg);
            wf[i] = ldfrag(&Ws[0][0], wn + 16*i + lr, 4*lg);
        }
#pragma unroll
        for (int m = 0; m < 4; ++m)
#pragma unroll
            for (int n = 0; n < 4; ++n)
                acc[m][n] = MFMA16(af[m], wf[n], acc[m][n]);
    }

    // D-layout: value(lane,reg) of subtile (msub,nsub) ->
    // C[bm+wm+16*msub+4*lg+reg][bn+wn+16*nsub+lr]
#pragma unroll
    for (int nsub = 0; nsub < 4; ++nsub) {
        const int n0 = bn + wn + 16*nsub + lr;
        const float bv = bias[n0];
#pragma unroll
        for (int msub = 0; msub < 4; ++msub) {
#pragma unroll
            for (int reg = 0; reg < 4; ++reg) {
                const int m = bm + wm + 16*msub + 4*lg + reg;
                float v = acc[msub][nsub][reg] + bv;
                if (MODE == 0) {
                    const int which = n0 >> 10;
                    const int e0 = n0 & 1023;
                    const int h = e0 >> 6, d0 = e0 & 63;
                    if (which == 0) v *= 0.125f;
                    unsigned short* dst = (which == 0) ? qbuf : (which == 1) ? kbuf : vbuf;
                    dst[((size_t)((m & 1)*Hh + h) * Tt + (m >> 1)) * HD + d0] = f2bf(v);
                } else {
                    Cout[(size_t)m * N + n0] = v;
                }
            }
        }
    }
}

// ---------------------------------------------------------------------------
// MFMA fused attention, bf16 in/out. Block = (bh, 128-row Q-tile),
// 512 threads = 8 waves; wave w owns t-rows [16w, 16w+16). Same per-element
// arithmetic as R10 (bit-identical); 2x resident waves for latency hiding.
// ---------------------------------------------------------------------------
__global__ __launch_bounds__(512)
void attn_mfma(const unsigned short* __restrict__ qb, const unsigned short* __restrict__ kb,
               const unsigned short* __restrict__ vb, const float* __restrict__ mask,
               unsigned short* __restrict__ attnb, float* __restrict__ lbuf)
{
    __shared__ unsigned short Ks[64][66];   // K tile [s][d] (also Q staging)
    __shared__ unsigned short Vt[64][66];   // V tile transposed [d][s-pairs]
    __shared__ float l_sh[128];

    const int tid  = threadIdx.x;
    const int bh   = blockIdx.x;           // b*16+h
    const int t0   = blockIdx.y * 128;
    const int w    = tid >> 6;             // wave 0..7
    const int lane = tid & 63;
    const int lr   = lane & 15;
    const int lg   = lane >> 4;            // k-group 0..3
    const int b = bh >> 4, h = bh & 15;

    const unsigned short* __restrict__ Qg = qb + (size_t)bh * Tt * HD;
    const unsigned short* __restrict__ Kg = kb + (size_t)bh * Tt * HD;
    const unsigned short* __restrict__ Vg = vb + (size_t)bh * Tt * HD;

    const int str = tid >> 3;              // staging row 0..63
    const int stc = (tid & 7) * 8;         // staging col (ushorts), 16B units

    // ---- Q fragments to registers (B-operand of swapped QK^T) ----
    bf16x8 qf[2];   // [d-half]
    for (int half = 0; half < 2; ++half) {
        __syncthreads();
        *(uint4*)&Ks[str][stc] =
            *(const uint4*)&Qg[(size_t)(t0 + half*64 + str) * HD + stc];
        __syncthreads();
        if ((w >> 2) == half) {
            const int r = 16*(w & 3) + lr;
            qf[0] = ldfrag(&Ks[0][0], r, 4*lg);        // d 0..31
            qf[1] = ldfrag(&Ks[0][0], r, 32 + 4*lg);   // d 32..63
        }
    }

    f32x4 oacc[4];
#pragma unroll
    for (int d = 0; d < 4; ++d)
        oacc[d] = f32x4{0.f, 0.f, 0.f, 0.f};
    float lacc = 0.f;

    for (int s0 = 0; s0 < Tt; s0 += 64) {
        __syncthreads();   // previous tile's fragment reads complete
        // stage K (row-major copy): 512 threads x 1 uint4
        *(uint4*)&Ks[str][stc] =
            *(const uint4*)&Kg[(size_t)(s0 + str) * HD + stc];
        {   // stage V transposed via halfword ops: 512 threads = 16 dg x 32 s2
            const int dg = tid & 15, s2 = tid >> 4;    // s2: 0..31
            const uint2 a = *(const uint2*)&Vg[(size_t)(s0 + 2*s2)     * HD + dg*4];
            const uint2 c = *(const uint2*)&Vg[(size_t)(s0 + 2*s2 + 1) * HD + dg*4];
            *(unsigned int*)&Vt[dg*4+0][2*s2] = (a.x & 0xFFFFu) | (c.x << 16);
            *(unsigned int*)&Vt[dg*4+1][2*s2] = (a.x >> 16)     | (c.x & 0xFFFF0000u);
            *(unsigned int*)&Vt[dg*4+2][2*s2] = (a.y & 0xFFFFu) | (c.y << 16);
            *(unsigned int*)&Vt[dg*4+3][2*s2] = (a.y >> 16)     | (c.y & 0xFFFF0000u);
        }
        __syncthreads();

        // QK^T (swapped): sacc[ssub] = S^T 16x16 tile (row=s, col=t)
        f32x4 sacc[4];
#pragma unroll
        for (int ssub = 0; ssub < 4; ++ssub) {
            const bf16x8 a0 = ldfrag(&Ks[0][0], 16*ssub + lr, 4*lg);
            const bf16x8 a1 = ldfrag(&Ks[0][0], 16*ssub + lr, 32 + 4*lg);
            f32x4 z = {0.f, 0.f, 0.f, 0.f};
            z = MFMA16(a0, qf[0], z);
            z = MFMA16(a1, qf[1], z);
            sacc[ssub] = z;
        }

        // exp(score + mask): P packed into PV A-fragments; l partial
        unsigned int pw[8];
        {
            float lt = 0.f;
            const float* __restrict__ mrow =
                &mask[(size_t)(t0 + 16*w + lr) * Tt + s0];
#pragma unroll
            for (int ssub = 0; ssub < 4; ++ssub) {
                const float4 mv = *(const float4*)&mrow[16*ssub + 4*lg];
                const float e0 = __expf(sacc[ssub][0] + mv.x);
                const float e1 = __expf(sacc[ssub][1] + mv.y);
                const float e2 = __expf(sacc[ssub][2] + mv.z);
                const float e3 = __expf(sacc[ssub][3] + mv.w);
                lt += (e0 + e1) + (e2 + e3);
                pw[ssub*2]     = pack2bf(e0, e1);
                pw[ssub*2 + 1] = pack2bf(e2, e3);
            }
            lt += __shfl_xor(lt, 16);
            lt += __shfl_xor(lt, 32);
            lacc += lt;
        }

        // PV: O[t][d] += P * V
        const uint4 ua = {pw[0], pw[1], pw[2], pw[3]};
        const uint4 ub = {pw[4], pw[5], pw[6], pw[7]};
#pragma unroll
        for (int dsub = 0; dsub < 4; ++dsub) {
            const bf16x8 b0 = ldfrag(&Vt[0][0], 16*dsub + lr, 4*lg);
            const bf16x8 b1 = ldfrag(&Vt[0][0], 16*dsub + lr, 32 + 4*lg);
            oacc[dsub] = MFMA16(__builtin_bit_cast(bf16x8, ua), b0, oacc[dsub]);
            oacc[dsub] = MFMA16(__builtin_bit_cast(bf16x8, ub), b1, oacc[dsub]);
        }
    }

    __syncthreads();
    if (lg == 0) l_sh[16*w + lr] = lacc;
    __syncthreads();
#pragma unroll
    for (int reg = 0; reg < 4; ++reg) {
        const int tl = 16*w + 4*lg + reg;
        const float inv = 1.f / l_sh[tl];
        const int t = t0 + tl;
#pragma unroll
        for (int dsub = 0; dsub < 4; ++dsub)
            attnb[((size_t)t * Bb + b) * Ee + h*HD + dsub*16 + lr] =
                f2bf(oacc[dsub][reg] * inv);
    }
    if (lg == 0)
        lbuf[(size_t)bh * Tt + t0 + 16*w + lr] = lacc;
}

// ---------------------------------------------------------------------------
// MFMA avg_w pass (bf16 Q/K in): block = (b, 64 t, 64 s); loops 16 heads.
// ---------------------------------------------------------------------------
__global__ __launch_bounds__(256)
void avg_probs_mfma(const unsigned short* __restrict__ qb, const unsigned short* __restrict__ kb,
                    const float* __restrict__ mask, const float* __restrict__ lbuf,
                    float* __restrict__ avg)
{
    __shared__ unsigned short Qs[64][66];
    __shared__ unsigned short Ksh[64][66];
    __shared__ float linv[16][64];

    const int tid  = threadIdx.x;
    const int b    = blockIdx.z;
    const int t0   = blockIdx.y * 64;
    const int s0   = blockIdx.x * 64;
    const int w    = tid >> 6;
    const int lane = tid & 63;
    const int lr   = lane & 15;
    const int lg   = lane >> 4;

    {   // stage 1/(16*l) for all 16 heads of this t-tile
        const int h = tid >> 4, tl = (tid & 15) * 4;
        const float4 lv = *(const float4*)&lbuf[(size_t)(b*Hh + h) * Tt + t0 + tl];
        linv[h][tl+0] = 1.f / (16.f * lv.x);
        linv[h][tl+1] = 1.f / (16.f * lv.y);
        linv[h][tl+2] = 1.f / (16.f * lv.z);
        linv[h][tl+3] = 1.f / (16.f * lv.w);
    }

    // mask fragments (value(lane,reg) at t=t0+16w+4lg+reg, s=s0+16ssub+lr)
    f32x4 mf[4];
#pragma unroll
    for (int ssub = 0; ssub < 4; ++ssub)
#pragma unroll
        for (int reg = 0; reg < 4; ++reg)
            mf[ssub][reg] = mask[(size_t)(t0 + 16*w + 4*lg + reg) * Tt + s0 + 16*ssub + lr];

    f32x4 av[4];
#pragma unroll
    for (int ssub = 0; ssub < 4; ++ssub) av[ssub] = f32x4{0.f, 0.f, 0.f, 0.f};

    const int str = tid >> 2;              // staging row 0..63
    const int stc = (tid & 3) * 16;        // staging col (ushorts)

    for (int h = 0; h < Hh; ++h) {
        const unsigned short* __restrict__ Qg = qb + (size_t)(b*Hh + h) * Tt * HD;
        const unsigned short* __restrict__ Kg = kb + (size_t)(b*Hh + h) * Tt * HD;
        __syncthreads();   // prev iter fragment reads done (h=0: orders linv too)
        {
            const unsigned short* Qp = &Qg[(size_t)(t0 + str) * HD + stc];
            const unsigned short* Kp = &Kg[(size_t)(s0 + str) * HD + stc];
            const uint4 q0 = *(const uint4*)Qp;
            const uint4 q1 = *(const uint4*)(Qp + 8);
            const uint4 k0 = *(const uint4*)Kp;
            const uint4 k1 = *(const uint4*)(Kp + 8);
            *(uint4*)&Qs[str][stc]      = q0;
            *(uint4*)&Qs[str][stc + 8]  = q1;
            *(uint4*)&Ksh[str][stc]     = k0;
            *(uint4*)&Ksh[str][stc + 8] = k1;
        }
        __syncthreads();

        const float lv0 = linv[h][16*w + 4*lg + 0];
        const float lv1 = linv[h][16*w + 4*lg + 1];
        const float lv2 = linv[h][16*w + 4*lg + 2];
        const float lv3 = linv[h][16*w + 4*lg + 3];

        const bf16x8 af0 = ldfrag(&Qs[0][0], 16*w + lr, 4*lg);
        const bf16x8 af1 = ldfrag(&Qs[0][0], 16*w + lr, 32 + 4*lg);
#pragma unroll
        for (int ssub = 0; ssub < 4; ++ssub) {
            const bf16x8 bf0 = ldfrag(&Ksh[0][0], 16*ssub + lr, 4*lg);
            const bf16x8 bf1 = ldfrag(&Ksh[0][0], 16*ssub + lr, 32 + 4*lg);
            f32x4 z = {0.f, 0.f, 0.f, 0.f};
            z = MFMA16(af0, bf0, z);
            z = MFMA16(af1, bf1, z);
            av[ssub][0] += __expf(z[0] + mf[ssub][0]) * lv0;
            av[ssub][1] += __expf(z[1] + mf[ssub][1]) * lv1;
            av[ssub][2] += __expf(z[2] + mf[ssub][2]) * lv2;
            av[ssub][3] += __expf(z[3] + mf[ssub][3]) * lv3;
        }
    }

#pragma unroll
    for (int ssub = 0; ssub < 4; ++ssub)
#pragma unroll
        for (int reg = 0; reg < 4; ++reg)
            avg[((size_t)b * Tt + t0 + 16*w + 4*lg + reg) * Tt + s0 + 16*ssub + lr] =
                av[ssub][reg];
}

// ---------------------------------------------------------------------------
extern "C" void kernel_launch(void* const* d_in, const int* in_sizes, int n_in,
                              void* d_out, int out_size, void* d_ws, size_t ws_size,
                              hipStream_t stream)
{
    (void)in_sizes; (void)n_in; (void)out_size; (void)ws_size;
    const float* query = (const float*)d_in[0];   // [T,B,E]
    const float* mask  = (const float*)d_in[1];   // [T,T]
    const float* Wqkv  = (const float*)d_in[2];   // [3E,E]
    const float* bqkv  = (const float*)d_in[3];   // [3E]
    const float* Wout  = (const float*)d_in[4];   // [E,E]
    const float* bout  = (const float*)d_in[5];   // [E]

    float* out = (float*)d_out;                   // [T,B,E]
    float* avg = out + (size_t)Tt * Bb * Ee;      // [B,T,T]

    const size_t S1 = (size_t)BHh * Tt * HD;      // 4,194,304
    unsigned short* wsu     = (unsigned short*)d_ws;
    unsigned short* qbuf    = wsu;                 // bf16, Q pre-scaled
    unsigned short* kbuf    = qbuf + S1;
    unsigned short* vbuf    = kbuf + S1;
    unsigned short* attnb   = vbuf + S1;           // bf16 [T*B][E]
    unsigned short* querybf = attnb + (size_t)Mm * Ee;
    unsigned short* wqkvbf  = querybf + (size_t)Mm * Ee;
    unsigned short* woutbf  = wqkvbf + (size_t)3 * Ee * Ee;
    float*          lbuf    = (float*)(woutbf + (size_t)Ee * Ee);

    // 0) prepack f32 weights/activations to bf16 (RNE; bit-identical to the
    //    rounding previously done inside the consumers)
    to_bf16<<<1024, 256, 0, stream>>>(query, querybf, (Mm*Ee)/8);
    to_bf16<<<1024, 256, 0, stream>>>(Wqkv, wqkvbf, (3*Ee*Ee)/8);
    to_bf16<<<512,  256, 0, stream>>>(Wout, woutbf, (Ee*Ee)/8);

    // 1) fused QKV projection (MFMA; scatter bf16 head-major, scale Q)
    gemm_mfma<0><<<dim3(3072/128, Mm/128), 256, 0, stream>>>(
        querybf, wqkvbf, bqkv, nullptr, qbuf, kbuf, vbuf, 3072, Ee);
    // 2) MFMA fused attention (l + PV), bf16 out — 8 waves/block
    attn_mfma<<<dim3(BHh, Tt/128), 512, 0, stream>>>(
        qbuf, kbuf, vbuf, mask, attnb, lbuf);
    // 3) head-averaged probs (MFMA)
    avg_probs_mfma<<<dim3(Tt/64, Tt/64, Bb), 256, 0, stream>>>(
        qbuf, kbuf, mask, lbuf, avg);
    // 4) output projection (MFMA)
    gemm_mfma<1><<<dim3(Ee/128, Mm/128), 256, 0, stream>>>(
        attnb, woutbf, bout, out, nullptr, nullptr, nullptr, Ee, Ee);
}

// Round 12
// 244.296 us; speedup vs baseline: 1.3374x; 1.0025x over previous
//
#include <hip/hip_runtime.h>
#include <cstdint>
#include <cstddef>

#define Tt 2048
#define Bb 2
#define Ee 1024
#define Hh 16
#define HD 64
#define BHh (Bb*Hh)
#define Mm (Tt*Bb)

typedef short bf16x8 __attribute__((ext_vector_type(8)));
typedef float f32x4  __attribute__((ext_vector_type(4)));

#define MFMA16(a,b,c) __builtin_amdgcn_mfma_f32_16x16x32_bf16(a, b, c, 0, 0, 0)

// Software RNE f32->bf16 (R7-validated; inline-asm v_cvt_pk_bf16_f32 is WRONG
// on this path — R8 failed with truncation-bias-magnitude error 1e-2).
__device__ __forceinline__ unsigned short f2bf(float f) {
    unsigned int u = __builtin_bit_cast(unsigned int, f);
    u += 0x7FFFu + ((u >> 16) & 1u);        // RNE
    return (unsigned short)(u >> 16);
}
__device__ __forceinline__ unsigned int pack2bf(float lo, float hi) {
    return (unsigned int)f2bf(lo) | ((unsigned int)f2bf(hi) << 16);
}

// R7-proven LDS fragment load, pitch 66 ushorts. Split k-slot convention:
// slot j<4 -> col+j, j>=4 -> col+16+(j-4). Same map used by both MFMA
// operands everywhere (+ forced P/V pairing) -> permutation-consistent.
__device__ __forceinline__ bf16x8 ldfrag(const unsigned short* base, int row, int col) {
    const unsigned int* p = (const unsigned int*)(base + row*66 + col);
    const unsigned int* q = (const unsigned int*)(base + row*66 + col + 16);
    uint4 u;
    u.x = p[0]; u.y = p[1];
    u.z = q[0]; u.w = q[1];
    return __builtin_bit_cast(bf16x8, u);
}

// ---------------------------------------------------------------------------
// f32 -> bf16 prepack (RNE), vectorized x8. n8 = n/8.
// ---------------------------------------------------------------------------
__global__ __launch_bounds__(256)
void to_bf16(const float* __restrict__ src, unsigned short* __restrict__ dst, int n8)
{
    const int stride = gridDim.x * 256;
    for (int i = blockIdx.x*256 + threadIdx.x; i < n8; i += stride) {
        const float4 a = ((const float4*)src)[2*i];
        const float4 b = ((const float4*)src)[2*i + 1];
        const uint4 u = {pack2bf(a.x,a.y), pack2bf(a.z,a.w),
                         pack2bf(b.x,b.y), pack2bf(b.z,b.w)};
        ((uint4*)dst)[i] = u;
    }
}

// ---------------------------------------------------------------------------
// MFMA GEMM on bf16 inputs: C[M,N] = A[M,K]*W[N,K]^T + bias[N].
// 128x128 tile, BK=32, 4 waves (2x2), wave = 64x64 out. R7 LDS machinery.
// MODE 0: scatter bf16 into head-major Q/K/V (scale Q by 0.125).
// MODE 1: f32 store to Cout.
// ---------------------------------------------------------------------------
template<int MODE>
__global__ __launch_bounds__(256)
void gemm_mfma(const unsigned short* __restrict__ A, const unsigned short* __restrict__ W,
               const float* __restrict__ bias, float* __restrict__ Cout,
               unsigned short* __restrict__ qbuf, unsigned short* __restrict__ kbuf,
               unsigned short* __restrict__ vbuf, int N, int K)
{
    __shared__ unsigned short As[128][66];
    __shared__ unsigned short Ws[128][66];
    const int tid  = threadIdx.x;
    const int bm   = blockIdx.y * 128;
    const int bn   = blockIdx.x * 128;
    const int w    = tid >> 6;
    const int lane = tid & 63;
    const int lr   = lane & 15;
    const int lg   = lane >> 4;
    const int wm   = (w >> 1) * 64;
    const int wn   = (w & 1) * 64;

    f32x4 acc[4][4];
#pragma unroll
    for (int m = 0; m < 4; ++m)
#pragma unroll
        for (int n = 0; n < 4; ++n)
            acc[m][n] = f32x4{0.f, 0.f, 0.f, 0.f};

    const int sr = tid >> 1;            // staging row 0..127
    const int sc = (tid & 1) * 16;      // staging col 0 / 16 (ushorts)

    for (int k0 = 0; k0 < K; k0 += 32) {
        __syncthreads();
        {
            const unsigned short* Ap = &A[(size_t)(bm + sr) * K + k0 + sc];
            const unsigned short* Wp = &W[(size_t)(bn + sr) * K + k0 + sc];
            const uint4 a0 = *(const uint4*)Ap;
            const uint4 a1 = *(const uint4*)(Ap + 8);
            const uint4 w0 = *(const uint4*)Wp;
            const uint4 w1 = *(const uint4*)(Wp + 8);
            *(uint4*)&As[sr][sc]     = a0;
            *(uint4*)&As[sr][sc + 8] = a1;
            *(uint4*)&Ws[sr][sc]     = w0;
            *(uint4*)&Ws[sr][sc + 8] = w1;
        }
        __syncthreads();

        bf16x8 af[4], wf[4];
#pragma unroll
        for (int i = 0; i < 4; ++i) {
            af[i] = ldfrag(&As[0][0], wm + 16*i + lr, 4*lg);
            wf[i] = ldfrag(&Ws[0][0], wn + 16*i + lr, 4*lg);
        }
#pragma unroll
        for (int m = 0; m < 4; ++m)
#pragma unroll
            for (int n = 0; n < 4; ++n)
                acc[m][n] = MFMA16(af[m], wf[n], acc[m][n]);
    }

    // D-layout: value(lane,reg) of subtile (msub,nsub) ->
    // C[bm+wm+16*msub+4*lg+reg][bn+wn+16*nsub+lr]
#pragma unroll
    for (int nsub = 0; nsub < 4; ++nsub) {
        const int n0 = bn + wn + 16*nsub + lr;
        const float bv = bias[n0];
#pragma unroll
        for (int msub = 0; msub < 4; ++msub) {
#pragma unroll
            for (int reg = 0; reg < 4; ++reg) {
                const int m = bm + wm + 16*msub + 4*lg + reg;
                float v = acc[msub][nsub][reg] + bv;
                if (MODE == 0) {
                    const int which = n0 >> 10;
                    const int e0 = n0 & 1023;
                    const int h = e0 >> 6, d0 = e0 & 63;
                    if (which == 0) v *= 0.125f;
                    unsigned short* dst = (which == 0) ? qbuf : (which == 1) ? kbuf : vbuf;
                    dst[((size_t)((m & 1)*Hh + h) * Tt + (m >> 1)) * HD + d0] = f2bf(v);
                } else {
                    Cout[(size_t)m * N + n0] = v;
                }
            }
        }
    }
}

// ---------------------------------------------------------------------------
// MFMA fused attention, bf16 in/out. 512 threads = 8 waves; wave w owns
// t-rows [16w, 16w+16) of a 128-row Q-tile. 1-D grid of 512 with XCD-aware
// remap: wid = (bid%8)*64 + bid/8 -> each XCD owns 2 t-tiles x all 32 bh,
// so the 1MB mask tile is fetched once per XCD (R11: 78MB fetch = 8x dup).
// ---------------------------------------------------------------------------
__global__ __launch_bounds__(512)
void attn_mfma(const unsigned short* __restrict__ qb, const unsigned short* __restrict__ kb,
               const unsigned short* __restrict__ vb, const float* __restrict__ mask,
               unsigned short* __restrict__ attnb, float* __restrict__ lbuf)
{
    __shared__ unsigned short Ks[64][66];   // K tile [s][d] (also Q staging)
    __shared__ unsigned short Vt[64][66];   // V tile transposed [d][s-pairs]
    __shared__ float l_sh[128];

    const int tid  = threadIdx.x;
    // XCD-aware remap (bijective: 512 = 8*64)
    const int bid  = blockIdx.x;
    const int wid  = (bid & 7) * 64 + (bid >> 3);
    const int bh   = wid & 31;             // b*16+h
    const int t0   = (wid >> 5) * 128;
    const int w    = tid >> 6;             // wave 0..7
    const int lane = tid & 63;
    const int lr   = lane & 15;
    const int lg   = lane >> 4;            // k-group 0..3
    const int b = bh >> 4, h = bh & 15;

    const unsigned short* __restrict__ Qg = qb + (size_t)bh * Tt * HD;
    const unsigned short* __restrict__ Kg = kb + (size_t)bh * Tt * HD;
    const unsigned short* __restrict__ Vg = vb + (size_t)bh * Tt * HD;

    const int str = tid >> 3;              // staging row 0..63
    const int stc = (tid & 7) * 8;         // staging col (ushorts), 16B units

    // ---- Q fragments to registers (B-operand of swapped QK^T) ----
    bf16x8 qf[2];   // [d-half]
    for (int half = 0; half < 2; ++half) {
        __syncthreads();
        *(uint4*)&Ks[str][stc] =
            *(const uint4*)&Qg[(size_t)(t0 + half*64 + str) * HD + stc];
        __syncthreads();
        if ((w >> 2) == half) {
            const int r = 16*(w & 3) + lr;
            qf[0] = ldfrag(&Ks[0][0], r, 4*lg);        // d 0..31
            qf[1] = ldfrag(&Ks[0][0], r, 32 + 4*lg);   // d 32..63
        }
    }

    f32x4 oacc[4];
#pragma unroll
    for (int d = 0; d < 4; ++d)
        oacc[d] = f32x4{0.f, 0.f, 0.f, 0.f};
    float lacc = 0.f;

    for (int s0 = 0; s0 < Tt; s0 += 64) {
        __syncthreads();   // previous tile's fragment reads complete
        // stage K (row-major copy): 512 threads x 1 uint4
        *(uint4*)&Ks[str][stc] =
            *(const uint4*)&Kg[(size_t)(s0 + str) * HD + stc];
        {   // stage V transposed via halfword ops: 512 threads = 16 dg x 32 s2
            const int dg = tid & 15, s2 = tid >> 4;    // s2: 0..31
            const uint2 a = *(const uint2*)&Vg[(size_t)(s0 + 2*s2)     * HD + dg*4];
            const uint2 c = *(const uint2*)&Vg[(size_t)(s0 + 2*s2 + 1) * HD + dg*4];
            *(unsigned int*)&Vt[dg*4+0][2*s2] = (a.x & 0xFFFFu) | (c.x << 16);
            *(unsigned int*)&Vt[dg*4+1][2*s2] = (a.x >> 16)     | (c.x & 0xFFFF0000u);
            *(unsigned int*)&Vt[dg*4+2][2*s2] = (a.y & 0xFFFFu) | (c.y << 16);
            *(unsigned int*)&Vt[dg*4+3][2*s2] = (a.y >> 16)     | (c.y & 0xFFFF0000u);
        }
        __syncthreads();

        // QK^T (swapped): sacc[ssub] = S^T 16x16 tile (row=s, col=t)
        f32x4 sacc[4];
#pragma unroll
        for (int ssub = 0; ssub < 4; ++ssub) {
            const bf16x8 a0 = ldfrag(&Ks[0][0], 16*ssub + lr, 4*lg);
            const bf16x8 a1 = ldfrag(&Ks[0][0], 16*ssub + lr, 32 + 4*lg);
            f32x4 z = {0.f, 0.f, 0.f, 0.f};
            z = MFMA16(a0, qf[0], z);
            z = MFMA16(a1, qf[1], z);
            sacc[ssub] = z;
        }

        // exp(score + mask): P packed into PV A-fragments; l partial
        unsigned int pw[8];
        {
            float lt = 0.f;
            const float* __restrict__ mrow =
                &mask[(size_t)(t0 + 16*w + lr) * Tt + s0];
#pragma unroll
            for (int ssub = 0; ssub < 4; ++ssub) {
                const float4 mv = *(const float4*)&mrow[16*ssub + 4*lg];
                const float e0 = __expf(sacc[ssub][0] + mv.x);
                const float e1 = __expf(sacc[ssub][1] + mv.y);
                const float e2 = __expf(sacc[ssub][2] + mv.z);
                const float e3 = __expf(sacc[ssub][3] + mv.w);
                lt += (e0 + e1) + (e2 + e3);
                pw[ssub*2]     = pack2bf(e0, e1);
                pw[ssub*2 + 1] = pack2bf(e2, e3);
            }
            lt += __shfl_xor(lt, 16);
            lt += __shfl_xor(lt, 32);
            lacc += lt;
        }

        // PV: O[t][d] += P * V
        const uint4 ua = {pw[0], pw[1], pw[2], pw[3]};
        const uint4 ub = {pw[4], pw[5], pw[6], pw[7]};
#pragma unroll
        for (int dsub = 0; dsub < 4; ++dsub) {
            const bf16x8 b0 = ldfrag(&Vt[0][0], 16*dsub + lr, 4*lg);
            const bf16x8 b1 = ldfrag(&Vt[0][0], 16*dsub + lr, 32 + 4*lg);
            oacc[dsub] = MFMA16(__builtin_bit_cast(bf16x8, ua), b0, oacc[dsub]);
            oacc[dsub] = MFMA16(__builtin_bit_cast(bf16x8, ub), b1, oacc[dsub]);
        }
    }

    __syncthreads();
    if (lg == 0) l_sh[16*w + lr] = lacc;
    __syncthreads();
#pragma unroll
    for (int reg = 0; reg < 4; ++reg) {
        const int tl = 16*w + 4*lg + reg;
        const float inv = 1.f / l_sh[tl];
        const int t = t0 + tl;
#pragma unroll
        for (int dsub = 0; dsub < 4; ++dsub)
            attnb[((size_t)t * Bb + b) * Ee + h*HD + dsub*16 + lr] =
                f2bf(oacc[dsub][reg] * inv);
    }
    if (lg == 0)
        lbuf[(size_t)bh * Tt + t0 + 16*w + lr] = lacc;
}

// ---------------------------------------------------------------------------
// MFMA avg_w pass (bf16 Q/K in): block = (b, 64 t, 64 s); loops 16 heads.
// ---------------------------------------------------------------------------
__global__ __launch_bounds__(256)
void avg_probs_mfma(const unsigned short* __restrict__ qb, const unsigned short* __restrict__ kb,
                    const float* __restrict__ mask, const float* __restrict__ lbuf,
                    float* __restrict__ avg)
{
    __shared__ unsigned short Qs[64][66];
    __shared__ unsigned short Ksh[64][66];
    __shared__ float linv[16][64];

    const int tid  = threadIdx.x;
    const int b    = blockIdx.z;
    const int t0   = blockIdx.y * 64;
    const int s0   = blockIdx.x * 64;
    const int w    = tid >> 6;
    const int lane = tid & 63;
    const int lr   = lane & 15;
    const int lg   = lane >> 4;

    {   // stage 1/(16*l) for all 16 heads of this t-tile
        const int h = tid >> 4, tl = (tid & 15) * 4;
        const float4 lv = *(const float4*)&lbuf[(size_t)(b*Hh + h) * Tt + t0 + tl];
        linv[h][tl+0] = 1.f / (16.f * lv.x);
        linv[h][tl+1] = 1.f / (16.f * lv.y);
        linv[h][tl+2] = 1.f / (16.f * lv.z);
        linv[h][tl+3] = 1.f / (16.f * lv.w);
    }

    // mask fragments (value(lane,reg) at t=t0+16w+4lg+reg, s=s0+16ssub+lr)
    f32x4 mf[4];
#pragma unroll
    for (int ssub = 0; ssub < 4; ++ssub)
#pragma unroll
        for (int reg = 0; reg < 4; ++reg)
            mf[ssub][reg] = mask[(size_t)(t0 + 16*w + 4*lg + reg) * Tt + s0 + 16*ssub + lr];

    f32x4 av[4];
#pragma unroll
    for (int ssub = 0; ssub < 4; ++ssub) av[ssub] = f32x4{0.f, 0.f, 0.f, 0.f};

    const int str = tid >> 2;              // staging row 0..63
    const int stc = (tid & 3) * 16;        // staging col (ushorts)

    for (int h = 0; h < Hh; ++h) {
        const unsigned short* __restrict__ Qg = qb + (size_t)(b*Hh + h) * Tt * HD;
        const unsigned short* __restrict__ Kg = kb + (size_t)(b*Hh + h) * Tt * HD;
        __syncthreads();   // prev iter fragment reads done (h=0: orders linv too)
        {
            const unsigned short* Qp = &Qg[(size_t)(t0 + str) * HD + stc];
            const unsigned short* Kp = &Kg[(size_t)(s0 + str) * HD + stc];
            const uint4 q0 = *(const uint4*)Qp;
            const uint4 q1 = *(const uint4*)(Qp + 8);
            const uint4 k0 = *(const uint4*)Kp;
            const uint4 k1 = *(const uint4*)(Kp + 8);
            *(uint4*)&Qs[str][stc]      = q0;
            *(uint4*)&Qs[str][stc + 8]  = q1;
            *(uint4*)&Ksh[str][stc]     = k0;
            *(uint4*)&Ksh[str][stc + 8] = k1;
        }
        __syncthreads();

        const float lv0 = linv[h][16*w + 4*lg + 0];
        const float lv1 = linv[h][16*w + 4*lg + 1];
        const float lv2 = linv[h][16*w + 4*lg + 2];
        const float lv3 = linv[h][16*w + 4*lg + 3];

        const bf16x8 af0 = ldfrag(&Qs[0][0], 16*w + lr, 4*lg);
        const bf16x8 af1 = ldfrag(&Qs[0][0], 16*w + lr, 32 + 4*lg);
#pragma unroll
        for (int ssub = 0; ssub < 4; ++ssub) {
            const bf16x8 bf0 = ldfrag(&Ksh[0][0], 16*ssub + lr, 4*lg);
            const bf16x8 bf1 = ldfrag(&Ksh[0][0], 16*ssub + lr, 32 + 4*lg);
            f32x4 z = {0.f, 0.f, 0.f, 0.f};
            z = MFMA16(af0, bf0, z);
            z = MFMA16(af1, bf1, z);
            av[ssub][0] += __expf(z[0] + mf[ssub][0]) * lv0;
            av[ssub][1] += __expf(z[1] + mf[ssub][1]) * lv1;
            av[ssub][2] += __expf(z[2] + mf[ssub][2]) * lv2;
            av[ssub][3] += __expf(z[3] + mf[ssub][3]) * lv3;
        }
    }

#pragma unroll
    for (int ssub = 0; ssub < 4; ++ssub)
#pragma unroll
        for (int reg = 0; reg < 4; ++reg)
            avg[((size_t)b * Tt + t0 + 16*w + 4*lg + reg) * Tt + s0 + 16*ssub + lr] =
                av[ssub][reg];
}

// ---------------------------------------------------------------------------
extern "C" void kernel_launch(void* const* d_in, const int* in_sizes, int n_in,
                              void* d_out, int out_size, void* d_ws, size_t ws_size,
                              hipStream_t stream)
{
    (void)in_sizes; (void)n_in; (void)out_size; (void)ws_size;
    const float* query = (const float*)d_in[0];   // [T,B,E]
    const float* mask  = (const float*)d_in[1];   // [T,T]
    const float* Wqkv  = (const float*)d_in[2];   // [3E,E]
    const float* bqkv  = (const float*)d_in[3];   // [3E]
    const float* Wout  = (const float*)d_in[4];   // [E,E]
    const float* bout  = (const float*)d_in[5];   // [E]

    float* out = (float*)d_out;                   // [T,B,E]
    float* avg = out + (size_t)Tt * Bb * Ee;      // [B,T,T]

    const size_t S1 = (size_t)BHh * Tt * HD;      // 4,194,304
    unsigned short* wsu     = (unsigned short*)d_ws;
    unsigned short* qbuf    = wsu;                 // bf16, Q pre-scaled
    unsigned short* kbuf    = qbuf + S1;
    unsigned short* vbuf    = kbuf + S1;
    unsigned short* attnb   = vbuf + S1;           // bf16 [T*B][E]
    unsigned short* querybf = attnb + (size_t)Mm * Ee;
    unsigned short* wqkvbf  = querybf + (size_t)Mm * Ee;
    unsigned short* woutbf  = wqkvbf + (size_t)3 * Ee * Ee;
    float*          lbuf    = (float*)(woutbf + (size_t)Ee * Ee);

    // 0) prepack f32 weights/activations to bf16 (RNE; bit-identical to the
    //    rounding previously done inside the consumers)
    to_bf16<<<1024, 256, 0, stream>>>(query, querybf, (Mm*Ee)/8);
    to_bf16<<<1024, 256, 0, stream>>>(Wqkv, wqkvbf, (3*Ee*Ee)/8);
    to_bf16<<<512,  256, 0, stream>>>(Wout, woutbf, (Ee*Ee)/8);

    // 1) fused QKV projection (MFMA; scatter bf16 head-major, scale Q)
    gemm_mfma<0><<<dim3(3072/128, Mm/128), 256, 0, stream>>>(
        querybf, wqkvbf, bqkv, nullptr, qbuf, kbuf, vbuf, 3072, Ee);
    // 2) MFMA fused attention (l + PV), bf16 out — 8 waves, XCD-swizzled grid
    attn_mfma<<<dim3(BHh * (Tt/128)), 512, 0, stream>>>(
        qbuf, kbuf, vbuf, mask, attnb, lbuf);
    // 3) head-averaged probs (MFMA)
    avg_probs_mfma<<<dim3(Tt/64, Tt/64, Bb), 256, 0, stream>>>(
        qbuf, kbuf, mask, lbuf, avg);
    // 4) output projection (MFMA)
    gemm_mfma<1><<<dim3(Ee/128, Mm/128), 256, 0, stream>>>(
        attnb, woutbf, bout, out, nullptr, nullptr, nullptr, Ee, Ee);
}